// Round 9
// baseline (170.264 us; speedup 1.0000x reference)
//
#include <hip/hip_runtime.h>
#include <stdint.h>

#pragma clang fp contract(off)

#define NMS_B 8
#define NMS_N 4096
#define NMS_NW 64       // 64-bit words per suppression row
#define ROIS 256

typedef unsigned long long u64;
typedef unsigned int u32;

__device__ __forceinline__ u64 rdlane_u64(u64 v, int l) {
    u32 lo = (u32)__builtin_amdgcn_readlane((int)(u32)v, l);
    u32 hi = (u32)__builtin_amdgcn_readlane((int)(u32)(v >> 32), l);
    return ((u64)hi << 32) | lo;
}
__device__ __forceinline__ u64 rdfirst_u64(u64 v) {
    u32 lo = (u32)__builtin_amdgcn_readfirstlane((int)(u32)v);
    u32 hi = (u32)__builtin_amdgcn_readfirstlane((int)(u32)(v >> 32));
    return ((u64)hi << 32) | lo;
}

// ---------------------------------------------------------------------------
// K1a: RANK BY COUNTING (replaces bitonic sort entirely — no barriers, no
// serial stage chain). rank_i = #{j : key_j < key_i}, key = (~score)<<32|idx
// (distinct keys -> exact permutation; identical order to argsort(-score)
// with index tie-break, same as the verified bitonic).
// Wave = one 64-row x 512-col tile-strip: lane = column, rows broadcast via
// scalar loads, one v_cmp+ballot+popcount per (row, colgroup). Partial rank
// for 64 rows x seg written coalesced. 512 waves/batch, 4096 total.
// ---------------------------------------------------------------------------
__global__ __launch_bounds__(64) void nms_rank(
        const float* __restrict__ in, u32* __restrict__ partial) {
    const int b = blockIdx.y;
    const int rg = blockIdx.x >> 3;            // row group 0..63
    const int seg = blockIdx.x & 7;            // col segment 0..7 (8 cgs each)
    const int lane = threadIdx.x;
    const size_t base = (size_t)b * NMS_N;

    const float* rowsc = in + (base + rg * 64) * 5;   // wave-uniform base

    u32 pr = 0;                                // partial rank of row `lane`
    #pragma unroll
    for (int cg = 0; cg < 8; ++cg) {
        int col = (seg * 8 + cg) * 64 + lane;
        float cs = in[(base + col) * 5];
        u64 ck = ((u64)(~__float_as_uint(cs)) << 32) | (u32)col;
        #pragma unroll 8
        for (int r = 0; r < 64; ++r) {
            float rs = rowsc[r * 5];           // uniform -> s_load
            u64 rk = ((u64)(~__float_as_uint(rs)) << 32) | (u32)(rg * 64 + r);
            u32 pc = (u32)__popcll(__ballot(ck < rk));
            if (lane == r) pr += pc;
        }
    }
    partial[((size_t)(b * 8 + seg)) * NMS_N + rg * 64 + lane] = pr;
}

// ---------------------------------------------------------------------------
// K1b: finish — sum the 8 partial ranks per element, compute corners
// (floor(w/2) exactly per reference) + HALF-areas (exact: small even ints),
// and SCATTER to sorted position: sortedIdx[rank]=i, crn[rank], ha[rank].
// ---------------------------------------------------------------------------
__global__ __launch_bounds__(256) void nms_finish(
        const float* __restrict__ in, const u32* __restrict__ partial,
        u32* __restrict__ sortedIdx, float4* __restrict__ crn,
        float* __restrict__ ha) {
    const int b = blockIdx.y;
    const int i = blockIdx.x * 256 + threadIdx.x;
    const size_t base = (size_t)b * NMS_N;

    u32 rank = 0;
    #pragma unroll
    for (int s = 0; s < 8; ++s)
        rank += partial[((size_t)(b * 8 + s)) * NMS_N + i];

    const float* bp = in + (base + i) * 5;
    float x = bp[1], y = bp[2], w = bp[3], h = bp[4];
    float ws_ = floorf(w * 0.5f);
    float hs_ = floorf(h * 0.5f);
    float X1 = x - ws_, Y1 = y - hs_, X2 = x + ws_, Y2 = y + hs_;

    size_t g = base + rank;
    sortedIdx[g] = (u32)i;
    crn[g] = make_float4(X1, Y1, X2, Y2);
    ha[g] = 0.5f * ((X2 - X1) * (Y2 - Y1));    // exact: area is a small int
}

// ---------------------------------------------------------------------------
// K2: suppression bitmask, ballot orientation, equal-work trapezoid grid.
// Diagonal units (rowblk==2wp, 2wp+1) also write the dense diag array
// diagw2[b][wp][r] = words (2wp,2wp+1) of row 128*wp+r — fully computed
// words (all bits valid IoU results). Unchanged from R8.
// ---------------------------------------------------------------------------
__global__ __launch_bounds__(256) void nms_mask(
        const float4* __restrict__ crn, const float* __restrict__ ha,
        u64* __restrict__ mask, u64* __restrict__ diagw2) {
    const int b = blockIdx.y;
    const int u = blockIdx.x * 4 + (threadIdx.x >> 6);   // unit id, 0..1055
    const int lane = threadIdx.x & 63;

    int wp = (int)sqrtf((float)u);
    while (wp * (wp + 1) > u) --wp;
    while ((wp + 1) * (wp + 2) <= u) ++wp;
    const int rowblk = u - wp * (wp + 1);                // 0..2*wp+1

    const size_t base = (size_t)b * NMS_N;
    const int c0 = wp * 128 + lane;
    float4 c0c = crn[base + c0];
    float4 c1c = crn[base + c0 + 64];
    float h0 = ha[base + c0];
    float h1 = ha[base + c0 + 64];

    const int rowbase = __builtin_amdgcn_readfirstlane(rowblk * 64);
    const float4* rowc = crn + base + rowbase;
    const float* rowh = ha + base + rowbase;

    u64 w0 = 0, w1 = 0;
    for (int rg = 0; rg < 64; rg += 8) {
        float fx1[8], fy1[8], fx2[8], fy2[8], fha[8];
        #pragma unroll
        for (int q = 0; q < 8; ++q) {                    // uniform -> s_load
            float4 rc = rowc[rg + q];
            fx1[q] = rc.x; fy1[q] = rc.y; fx2[q] = rc.z; fy2[q] = rc.w;
            fha[q] = rowh[rg + q];
        }
        #pragma unroll
        for (int q = 0; q < 8; ++q) {
            float iw0 = fmaxf(fminf(fx2[q], c0c.z) - fmaxf(fx1[q], c0c.x), 0.0f);
            float ih0 = fmaxf(fminf(fy2[q], c0c.w) - fmaxf(fy1[q], c0c.y), 0.0f);
            float in0 = iw0 * ih0;
            bool p0 = in0 > fmaf(-0.5f, in0, fha[q] + h0);

            float iw1 = fmaxf(fminf(fx2[q], c1c.z) - fmaxf(fx1[q], c1c.x), 0.0f);
            float ih1 = fmaxf(fminf(fy2[q], c1c.w) - fmaxf(fy1[q], c1c.y), 0.0f);
            float in1 = iw1 * ih1;
            bool p1 = in1 > fmaf(-0.5f, in1, fha[q] + h1);

            u64 b0 = __ballot(p0);
            u64 b1 = __ballot(p1);
            if (lane == rg + q) { w0 = b0; w1 = b1; }
        }
    }

    ulonglong2 v; v.x = w0; v.y = w1;
    *(ulonglong2*)&mask[(base + rowbase + lane) * NMS_NW + wp * 2] = v;

    if (rowblk == 2 * wp || rowblk == 2 * wp + 1) {      // diagonal unit
        int r = ((rowblk & 1) << 6) + lane;              // row offset in 128-window
        *(ulonglong2*)&diagw2[(((size_t)b * 32 + wp) * 128 + r) * 2] = v;
    }
}

// ---------------------------------------------------------------------------
// K3: greedy scan (R8 version, unchanged): 64-row windows, stateless curwin
// gather over kept[], single u64 OR-butterfly, scalar ctz loop, dense
// diagw2 prefetch for nextdiag.
// ---------------------------------------------------------------------------
__global__ __launch_bounds__(64, 1) void nms_scan(
        const float* __restrict__ in, const u64* __restrict__ mask,
        const u64* __restrict__ diagw2, const u32* __restrict__ sortedIdx,
        float* __restrict__ outp) {
    const int b = blockIdx.x, lane = threadIdx.x;
    const u64* M = mask + (size_t)b * NMS_N * NMS_NW;
    const u64* D = diagw2 + (size_t)b * 32 * 128 * 2;

    __shared__ int kept[ROIS];
    for (int r = lane; r < ROIS; r += 64) kept[r] = 0;   // safety fallback

    int count = 0;
    // diag for window 0 (rows 0..63, word 0): diagw2 wp=0, h=0
    u64 diag = D[(size_t)lane * 2];

    for (int W = 0; W < 64 && count < ROIS; ++W) {
        // prefetch next window's diagonal from the DENSE array
        u64 nextdiag = 0;
        if (W + 1 < 64) {
            const int Wn = W + 1, Wp = Wn >> 1, h = Wn & 1;
            nextdiag = D[((size_t)Wp * 128 + (h << 6) + lane) * 2 + h];
        }

        // ---- curwin: OR of kept rows' word W ----
        u64 curwin = 0;
        if (count > 0) {
            const int cm1 = count - 1;
            u64 acc = 0;
            #pragma unroll
            for (int s = 0; s < 4; ++s) {                // 4 independent loads
                int j = lane + s * 64;
                int jj = j <= cm1 ? j : cm1;
                int pos = kept[jj];
                u64 v = M[(size_t)pos * NMS_NW + W];
                if (j <= cm1) acc |= v;
            }
            #pragma unroll
            for (int d2 = 1; d2 < 64; d2 <<= 1)          // OR-butterfly
                acc |= (u64)__shfl_xor((long long)acc, d2, 64);
            curwin = rdfirst_u64(acc);
        }

        // ---- serial scalar ctz-skip scan of this window ----
        u64 avail = ~curwin;
        while (avail != 0 && count < ROIS) {
            int r = __builtin_ctzll(avail);
            u64 d = rdlane_u64(diag, r);
            if (lane == 0) kept[count] = W * 64 + r;
            ++count;
            avail &= ~(d | (1ULL << r));
        }

        diag = nextdiag;
    }

    __syncthreads();
    for (int r = lane; r < ROIS; r += 64) {
        int pos = kept[r];
        int orig = (int)sortedIdx[(size_t)b * NMS_N + pos];
        const float* bp = in + ((size_t)b * NMS_N + orig) * 5;
        float4 o = make_float4(bp[1], bp[2], bp[3], bp[4]);
        ((float4*)outp)[(size_t)b * ROIS + r] = o;
    }
}

extern "C" void kernel_launch(void* const* d_in, const int* in_sizes, int n_in,
                              void* d_out, int out_size, void* d_ws, size_t ws_size,
                              hipStream_t stream) {
    const float* in = (const float*)d_in[0];
    float* out = (float*)d_out;
    char* ws = (char*)d_ws;

    u64* mask = (u64*)ws;                                          // 16 MB
    size_t off = (size_t)NMS_B * NMS_N * NMS_NW * sizeof(u64);
    u32* sortedIdx = (u32*)(ws + off); off += (size_t)NMS_B * NMS_N * 4;
    float4* crn = (float4*)(ws + off); off += (size_t)NMS_B * NMS_N * 16;
    float* ha = (float*)(ws + off);    off += (size_t)NMS_B * NMS_N * 4;
    u32* partial = (u32*)(ws + off);   off += (size_t)NMS_B * 8 * NMS_N * 4;
    u64* diagw2 = (u64*)(ws + off);    off += (size_t)NMS_B * 32 * 128 * 2 * 8;

    nms_rank<<<dim3(512, NMS_B), 64, 0, stream>>>(in, partial);
    nms_finish<<<dim3(16, NMS_B), 256, 0, stream>>>(in, partial, sortedIdx, crn, ha);
    nms_mask<<<dim3(264, NMS_B), 256, 0, stream>>>(crn, ha, mask, diagw2);
    nms_scan<<<NMS_B, 64, 0, stream>>>(in, mask, diagw2, sortedIdx, out);
}